// Round 2
// baseline (197.953 us; speedup 1.0000x reference)
//
#include <hip/hip_runtime.h>

// Output: (B=8, C=256, H=128, W=128) fp32.
//   c < 128 : out[b,c,i,j] = (c even ? sin : cos)(i / dim_t[c])
//   c >= 128: out[b,c,i,j] = (k even ? sin : cos)(j / dim_t[k]), k = c-128
//   dim_t[k] = 10000^((k & ~1) / 256)
// Pure-write kernel: compute one batch image's float4 per thread, replicate
// across the 8 batch copies (value is batch-independent).
//
// NOTE: use __builtin_amdgcn_* transcendentals — the __sinf/__exp2f names
// collide with glibc math.h declarations under -x hip on this toolchain.
// v_sin_f32 / v_cos_f32 take input in REVOLUTIONS: sin(x) = v_sin(x / 2pi).

#define PB 8
#define PC 256
#define PH 128
#define PW 128
#define PHALF 128

__global__ __launch_bounds__(256) void posenc2d_kernel(float* __restrict__ out) {
    const int tid = blockIdx.x * blockDim.x + threadIdx.x;  // 0 .. 256*128*32 - 1
    const int j4 = tid & 31;          // which float4 in the W row (32 per row)
    const int i  = (tid >> 5) & 127;  // H index
    const int c  = tid >> 12;         // channel 0..255

    const float LOG2_10000 = 13.287712379549449f;   // log2(10000)
    const float INV_2PI    = 0.15915494309189535f;  // 1/(2*pi)

    float4 v;
    if (c < PHALF) {
        // value depends only on (c, i): splat across the 4 j's
        const float inv_dt = __builtin_amdgcn_exp2f(-LOG2_10000 * (float)(c & ~1) * (1.0f / 256.0f));
        const float r = (float)i * inv_dt * INV_2PI;  // revolutions
        const float val = (c & 1) ? __builtin_amdgcn_cosf(r) : __builtin_amdgcn_sinf(r);
        v = make_float4(val, val, val, val);
    } else {
        const int k = c - PHALF;
        const float inv_dt = __builtin_amdgcn_exp2f(-LOG2_10000 * (float)(k & ~1) * (1.0f / 256.0f));
        const int j0 = j4 << 2;
        float vals[4];
#pragma unroll
        for (int t = 0; t < 4; ++t) {
            const float r = (float)(j0 + t) * inv_dt * INV_2PI;  // revolutions
            vals[t] = (k & 1) ? __builtin_amdgcn_cosf(r) : __builtin_amdgcn_sinf(r);
        }
        v = make_float4(vals[0], vals[1], vals[2], vals[3]);
    }

    // Replicate across the 8 batch copies. Consecutive threads write
    // consecutive 16B chunks within each batch image -> fully coalesced.
    float4* p = (float4*)out + tid;
    const size_t batch_stride4 = (size_t)PC * PH * PW / 4;  // float4 units
#pragma unroll
    for (int b = 0; b < PB; ++b) {
        p[(size_t)b * batch_stride4] = v;
    }
}

extern "C" void kernel_launch(void* const* d_in, const int* in_sizes, int n_in,
                              void* d_out, int out_size, void* d_ws, size_t ws_size,
                              hipStream_t stream) {
    (void)d_in; (void)in_sizes; (void)n_in; (void)d_ws; (void)ws_size; (void)out_size;
    float* out = (float*)d_out;
    // threads = C*H*(W/4) = 256*128*32 = 1,048,576 ; block 256 -> grid 4096
    posenc2d_kernel<<<4096, 256, 0, stream>>>(out);
}

// Round 6
// 193.414 us; speedup vs baseline: 1.0235x; 1.0235x over previous
//
#include <hip/hip_runtime.h>

// Output: (B=8, C=256, H=128, W=128) fp32.
//   c < 128 : out[b,c,i,j] = (c even ? sin : cos)(i / dim_t[c])
//   c >= 128: out[b,c,i,j] = (k even ? sin : cos)(j / dim_t[k]), k = c-128
//   dim_t[k] = 10000^((k & ~1) / 256)
//
// Pure-write, memory-bound. Single LINEAR write stream: one float4 per
// thread over the whole 2^23-float4 output; value recomputed per batch copy
// (b = tid>>20 is decoded implicitly and unused — value is b-independent).
//
// R4/R5 post-mortem: core dumps were an OOB write — I launched 131072
// blocks (4x the correct 32768), writing 512 MiB into the 128 MiB buffer.
// Total float4s = 8*256*128*128/4 = 8,388,608 = 2^23 -> grid 32768 x 256.
//
// NOTE: __builtin_amdgcn_* transcendentals — the __sinf/__exp2f names
// collide with glibc math.h under -x hip. v_sin/v_cos take REVOLUTIONS.

__global__ __launch_bounds__(256) void posenc2d_kernel(float* __restrict__ out) {
    const unsigned tid = blockIdx.x * blockDim.x + threadIdx.x;  // float4 index, 0..2^23-1
    // Per-batch image = 256*128*128/4 = 2^20 float4s.
    const int j4 = tid & 31;          // float4 within W row
    const int i  = (tid >> 5) & 127;  // H index
    const int c  = (tid >> 12) & 255; // channel (b = tid >> 20, unused)

    const float LOG2_10000 = 13.287712379549449f;   // log2(10000)
    const float INV_2PI    = 0.15915494309189535f;  // 1/(2*pi)

    float4 v;
    if (c < 128) {
        // value depends only on (c, i): splat across the 4 j's
        const float inv_dt = __builtin_amdgcn_exp2f(-LOG2_10000 * (float)(c & ~1) * (1.0f / 256.0f));
        const float r = (float)i * inv_dt * INV_2PI;  // revolutions
        const float val = (c & 1) ? __builtin_amdgcn_cosf(r) : __builtin_amdgcn_sinf(r);
        v = make_float4(val, val, val, val);
    } else {
        const int k = c - 128;
        const float inv_dt = __builtin_amdgcn_exp2f(-LOG2_10000 * (float)(k & ~1) * (1.0f / 256.0f));
        const float s = inv_dt * INV_2PI;
        const int j0 = j4 << 2;
        float vals[4];
#pragma unroll
        for (int t = 0; t < 4; ++t) {
            const float r = (float)(j0 + t) * s;  // revolutions
            vals[t] = (k & 1) ? __builtin_amdgcn_cosf(r) : __builtin_amdgcn_sinf(r);
        }
        v = make_float4(vals[0], vals[1], vals[2], vals[3]);
    }

    // Perfectly linear device-wide write stream.
    ((float4*)out)[tid] = v;
}

extern "C" void kernel_launch(void* const* d_in, const int* in_sizes, int n_in,
                              void* d_out, int out_size, void* d_ws, size_t ws_size,
                              hipStream_t stream) {
    (void)d_in; (void)in_sizes; (void)n_in; (void)d_ws; (void)ws_size; (void)out_size;
    float* out = (float*)d_out;
    // float4s = 8*256*128*128/4 = 8,388,608 = 2^23 ; block 256 -> grid 32768
    posenc2d_kernel<<<32768, 256, 0, stream>>>(out);
}